// Round 10
// baseline (88.909 us; speedup 1.0000x reference)
//
#include <hip/hip_runtime.h>
#include <hip/hip_bf16.h>

// B=8, T=1024, D=384, K=4
// loss = mean_{b,t,s} exp(-sum_k gt[b,t,s,k]^2/(2 sigma_k^2)) *
//        (||z[b,t]||^2 + ||z[b,s]||^2 - 2 z[b,t].z[b,s])
//
// Two-phase: phase 1 (gram_d2) computes dist2 -> bf16 ws (no gt stream);
// phase 2 (stream_loss) is a barrier-free 2-deep pipelined stream.

typedef float  f32x4   __attribute__((ext_vector_type(4)));
typedef short  bf16x8  __attribute__((ext_vector_type(8)));
typedef unsigned short ushort4_t __attribute__((ext_vector_type(4)));

#define T_DIM 1024
#define D_DIM 384

__device__ __forceinline__ unsigned short f32_bf16(float f) {
    unsigned int u = __float_as_uint(f);
    u += 0x7FFFu + ((u >> 16) & 1u);      // RNE
    return (unsigned short)(u >> 16);
}

// ---------------- prep: sq[b*T+t] = sum_d z^2 (exact f32) ----------------
__global__ void prep_sq(const float* __restrict__ z, float* __restrict__ sq) {
    int row  = blockIdx.x;           // 0..8191
    int lane = threadIdx.x;          // 64
    const float* zr = z + (size_t)row * D_DIM;
    float s = 0.f;
#pragma unroll
    for (int q = 0; q < 6; ++q) {
        float x = zr[lane + 64 * q];
        s += x * x;
    }
#pragma unroll
    for (int off = 32; off; off >>= 1) s += __shfl_down(s, off);
    if (lane == 0) sq[row] = s;
}

// ---------------- phase 1: dist2 tile -> bf16 (no gt) ----------------
// grid 512 = 8 b * 16 t-tiles * 4 s-groups; block 256 (4 waves x 16 t-rows).
// LDS trimmed to 49.4 KiB -> 3 blocks/CU for staging-latency hiding.
__launch_bounds__(256, 3)
__global__ void gram_d2(const float* __restrict__ z,
                        const float* __restrict__ sq,
                        unsigned short* __restrict__ d2w) {
    __shared__ unsigned short Blds[64 * D_DIM];   // 48 KiB, XOR-swizzled rows
    __shared__ float sqT_s[64];                   // this block's 64 t-rows
    __shared__ float sqS_s[256];                  // this block's 256 s-cols

    const int bid   = blockIdx.x;                 // 512
    const int b     = bid >> 6;
    const int tt    = (bid >> 2) & 15;
    const int sgrp  = bid & 3;
    const int t0    = tt * 64;
    const int sbase = sgrp * 256;

    const int tid  = threadIdx.x;
    const int lane = tid & 63, w = tid >> 6;
    const int l15  = lane & 15, lq = lane >> 4;

    const float* zb = z + (size_t)b * T_DIM * D_DIM;
    char* bb = (char*)Blds;

    if (tid < 64) sqT_s[tid] = sq[b * T_DIM + t0 + tid];
    sqS_s[tid] = sq[b * T_DIM + sbase + tid];

    // A fragments once: row = t0 + w*16 + l15, cols kk*32 + lq*8 .. +8
    bf16x8 af[12];
    {
        const float* Ar = zb + (size_t)(t0 + w * 16 + l15) * D_DIM + lq * 8;
#pragma unroll
        for (int kk = 0; kk < 12; ++kk) {
            float4 lo = *(const float4*)(Ar + kk * 32);
            float4 hi = *(const float4*)(Ar + kk * 32 + 4);
            bf16x8 t;
            t[0] = (short)f32_bf16(lo.x); t[1] = (short)f32_bf16(lo.y);
            t[2] = (short)f32_bf16(lo.z); t[3] = (short)f32_bf16(lo.w);
            t[4] = (short)f32_bf16(hi.x); t[5] = (short)f32_bf16(hi.y);
            t[6] = (short)f32_bf16(hi.z); t[7] = (short)f32_bf16(hi.w);
            af[kk] = t;
        }
    }

    for (int j = 0; j < 4; ++j) {
        const int s0 = sbase + j * 64;
        // stage 64-row B tile (s-rows), f32 -> bf16, XOR-swizzled
#pragma unroll
        for (int rp = 0; rp < 2; ++rp) {
            int row = rp * 32 + (tid >> 3);
            const float* src = zb + (size_t)(s0 + row) * D_DIM + (tid & 7) * 4;
            int base = row * 768 + (tid & 7) * 8;
            int sw   = (row & 7) << 4;
#pragma unroll
            for (int it = 0; it < 12; ++it) {
                float4 v = *(const float4*)(src + it * 32);
                ushort4_t h = { f32_bf16(v.x), f32_bf16(v.y),
                                f32_bf16(v.z), f32_bf16(v.w) };
                *(ushort4_t*)(bb + ((base + it * 64) ^ sw)) = h;
            }
        }
        __syncthreads();

        f32x4 acc[4] = {};
#pragma unroll
        for (int kk = 0; kk < 12; ++kk) {
#pragma unroll
            for (int nt = 0; nt < 4; ++nt) {
                int row = nt * 16 + l15;
                int off = (row * 768 + kk * 64 + lq * 16) ^ ((row & 7) << 4);
                bf16x8 bf = *(const bf16x8*)(bb + off);
                // SWAPPED operands: D row (lq*4+r) = s-local, D col (l15) = t-local
                acc[nt] = __builtin_amdgcn_mfma_f32_16x16x32_bf16(bf, af[kk], acc[nt], 0, 0, 0);
            }
        }
        __syncthreads();   // B reads done before next-j restage

        // epilogue: d2 = sqT + sqS - 2*gram -> packed bf16x4 store along s
        {
            const int tl = w * 16 + l15;
            const float td = sqT_s[tl];
            const int t = t0 + tl;
#pragma unroll
            for (int nt = 0; nt < 4; ++nt) {
                const int sl = j * 64 + nt * 16 + lq * 4;   // local s in [0,256)
                ushort4_t h;
#pragma unroll
                for (int r = 0; r < 4; ++r) {
                    float d2 = td + sqS_s[sl + r] - 2.0f * acc[nt][r];
                    h[r] = f32_bf16(d2);
                }
                *(ushort4_t*)&d2w[((size_t)b << 20) + ((size_t)t << 10) + sbase + sl] = h;
            }
        }
    }
}

// ---------------- phase 2: 2-deep pipelined stream over gt + d2 ----------------
// 1024 blocks x 256 threads; 32 elements/thread = 4 batches of 8.
// Always >=1 batch (8KB/wave) in flight: LOAD(q+1) issued before CONSUME(q).
// Named register sets (gA/gB) -> static indexing, no scratch.
__launch_bounds__(256, 4)
__global__ void stream_loss(const float* __restrict__ gt,
                            const unsigned short* __restrict__ d2w,
                            const float* __restrict__ sigma,
                            float* __restrict__ partials) {
    __shared__ float red[4];
    const float LOG2E = 1.4426950408889634f;
    const float i0 = LOG2E * 0.5f / (sigma[0] * sigma[0]);
    const float i1 = LOG2E * 0.5f / (sigma[1] * sigma[1]);
    const float i2 = LOG2E * 0.5f / (sigma[2] * sigma[2]);
    const float i3 = LOG2E * 0.5f / (sigma[3] * sigma[3]);

    const int base = blockIdx.x * 256 + threadIdx.x;   // 262144 threads, 1<<18
    const float4* gt4 = (const float4*)gt;

    float4 gA[8], gB[8];
    unsigned int dA[8], dB[8];
    float acc = 0.f;

#define LOAD_BATCH(G, D, q)                                                    \
    _Pragma("unroll")                                                          \
    for (int i = 0; i < 8; ++i) D[i] = d2w[((size_t)((q) * 8 + i) << 18) + base]; \
    _Pragma("unroll")                                                          \
    for (int i = 0; i < 8; ++i) G[i] = gt4[((size_t)((q) * 8 + i) << 18) + base];

#define CONSUME_BATCH(G, D)                                                    \
    _Pragma("unroll")                                                          \
    for (int i = 0; i < 8; ++i) {                                              \
        float4 gv = G[i];                                                      \
        float ddf = __uint_as_float(D[i] << 16);                               \
        float kv = gv.x * gv.x * i0 + gv.y * gv.y * i1                         \
                 + gv.z * gv.z * i2 + gv.w * gv.w * i3;                        \
        acc += exp2f(-kv) * ddf;                                               \
    }

    LOAD_BATCH(gA, dA, 0)
    LOAD_BATCH(gB, dB, 1)
    CONSUME_BATCH(gA, dA)       // batch1 (8KB/wave) in flight during this
    LOAD_BATCH(gA, dA, 2)
    CONSUME_BATCH(gB, dB)       // batch2 in flight
    LOAD_BATCH(gB, dB, 3)
    CONSUME_BATCH(gA, dA)       // batch3 in flight
    CONSUME_BATCH(gB, dB)

#undef LOAD_BATCH
#undef CONSUME_BATCH

    int lane = threadIdx.x & 63, w = threadIdx.x >> 6;
#pragma unroll
    for (int off = 32; off; off >>= 1) acc += __shfl_down(acc, off);
    if (lane == 0) red[w] = acc;
    __syncthreads();
    if (threadIdx.x == 0) partials[blockIdx.x] = red[0] + red[1] + red[2] + red[3];
}

// ---------------- deterministic final reduction (1024 partials) ----------------
__global__ void final_reduce(const float* __restrict__ partials, float* __restrict__ out) {
    __shared__ float red[4];
    int tid = threadIdx.x;  // 256
    float s = partials[tid] + partials[tid + 256] + partials[tid + 512] + partials[tid + 768];
#pragma unroll
    for (int off = 32; off; off >>= 1) s += __shfl_down(s, off);
    if ((tid & 63) == 0) red[tid >> 6] = s;
    __syncthreads();
    if (tid == 0) out[0] = (red[0] + red[1] + red[2] + red[3]) * (1.0f / 8388608.0f);
}

extern "C" void kernel_launch(void* const* d_in, const int* in_sizes, int n_in,
                              void* d_out, int out_size, void* d_ws, size_t ws_size,
                              hipStream_t stream) {
    const float* z     = (const float*)d_in[0];   // [8,1024,384]
    const float* gt    = (const float*)d_in[1];   // [8,1024,1024,4]
    const float* sigma = (const float*)d_in[2];   // [4]
    float* out = (float*)d_out;

    float* sq            = (float*)d_ws;                    // 8192 f32
    float* partials      = sq + 8192;                       // 1024 f32
    unsigned short* d2w  = (unsigned short*)(sq + 10240);   // 8.4M bf16 = 16.8 MB

    prep_sq<<<8192, 64, 0, stream>>>(z, sq);
    gram_d2<<<512, 256, 0, stream>>>(z, sq, d2w);
    stream_loss<<<1024, 256, 0, stream>>>(gt, d2w, sigma, partials);
    final_reduce<<<1, 256, 0, stream>>>(partials, out);
}

// Round 11
// 83.177 us; speedup vs baseline: 1.0689x; 1.0689x over previous
//
#include <hip/hip_runtime.h>
#include <hip/hip_bf16.h>

// B=8, T=1024, D=384, K=4
// loss = mean_{b,t,s} exp(-sum_k gt[b,t,s,k]^2/(2 sigma_k^2)) *
//        (||z[b,t]||^2 + ||z[b,s]||^2 - 2 z[b,t].z[b,s])
//
// Two-phase: phase 1 (gram_d2) computes dist2 -> bf16 ws (no gt stream);
// phase 2 (stream_loss) is a persistent 8-deep-loop 2-deep-pipelined stream.

typedef float  f32x4   __attribute__((ext_vector_type(4)));
typedef short  bf16x8  __attribute__((ext_vector_type(8)));
typedef unsigned short ushort4_t __attribute__((ext_vector_type(4)));

#define T_DIM 1024
#define D_DIM 384

__device__ __forceinline__ unsigned short f32_bf16(float f) {
    unsigned int u = __float_as_uint(f);
    u += 0x7FFFu + ((u >> 16) & 1u);      // RNE
    return (unsigned short)(u >> 16);
}

// ---------------- prep: sq[b*T+t] = sum_d z^2 (exact f32) ----------------
__global__ void prep_sq(const float* __restrict__ z, float* __restrict__ sq) {
    int row  = blockIdx.x;           // 0..8191
    int lane = threadIdx.x;          // 64
    const float* zr = z + (size_t)row * D_DIM;
    float s = 0.f;
#pragma unroll
    for (int q = 0; q < 6; ++q) {
        float x = zr[lane + 64 * q];
        s += x * x;
    }
#pragma unroll
    for (int off = 32; off; off >>= 1) s += __shfl_down(s, off);
    if (lane == 0) sq[row] = s;
}

// ---------------- phase 1: dist2 tile -> bf16 (no gt) ---------------- 
// (unchanged from round 10: swapped-operand MFMA, packed ushort4 stores,
//  49.4 KiB LDS -> 3 blocks/CU)
__launch_bounds__(256, 3)
__global__ void gram_d2(const float* __restrict__ z,
                        const float* __restrict__ sq,
                        unsigned short* __restrict__ d2w) {
    __shared__ unsigned short Blds[64 * D_DIM];   // 48 KiB, XOR-swizzled rows
    __shared__ float sqT_s[64];
    __shared__ float sqS_s[256];

    const int bid   = blockIdx.x;                 // 512
    const int b     = bid >> 6;
    const int tt    = (bid >> 2) & 15;
    const int sgrp  = bid & 3;
    const int t0    = tt * 64;
    const int sbase = sgrp * 256;

    const int tid  = threadIdx.x;
    const int lane = tid & 63, w = tid >> 6;
    const int l15  = lane & 15, lq = lane >> 4;

    const float* zb = z + (size_t)b * T_DIM * D_DIM;
    char* bb = (char*)Blds;

    if (tid < 64) sqT_s[tid] = sq[b * T_DIM + t0 + tid];
    sqS_s[tid] = sq[b * T_DIM + sbase + tid];

    bf16x8 af[12];
    {
        const float* Ar = zb + (size_t)(t0 + w * 16 + l15) * D_DIM + lq * 8;
#pragma unroll
        for (int kk = 0; kk < 12; ++kk) {
            float4 lo = *(const float4*)(Ar + kk * 32);
            float4 hi = *(const float4*)(Ar + kk * 32 + 4);
            bf16x8 t;
            t[0] = (short)f32_bf16(lo.x); t[1] = (short)f32_bf16(lo.y);
            t[2] = (short)f32_bf16(lo.z); t[3] = (short)f32_bf16(lo.w);
            t[4] = (short)f32_bf16(hi.x); t[5] = (short)f32_bf16(hi.y);
            t[6] = (short)f32_bf16(hi.z); t[7] = (short)f32_bf16(hi.w);
            af[kk] = t;
        }
    }

    for (int j = 0; j < 4; ++j) {
        const int s0 = sbase + j * 64;
#pragma unroll
        for (int rp = 0; rp < 2; ++rp) {
            int row = rp * 32 + (tid >> 3);
            const float* src = zb + (size_t)(s0 + row) * D_DIM + (tid & 7) * 4;
            int base = row * 768 + (tid & 7) * 8;
            int sw   = (row & 7) << 4;
#pragma unroll
            for (int it = 0; it < 12; ++it) {
                float4 v = *(const float4*)(src + it * 32);
                ushort4_t h = { f32_bf16(v.x), f32_bf16(v.y),
                                f32_bf16(v.z), f32_bf16(v.w) };
                *(ushort4_t*)(bb + ((base + it * 64) ^ sw)) = h;
            }
        }
        __syncthreads();

        f32x4 acc[4] = {};
#pragma unroll
        for (int kk = 0; kk < 12; ++kk) {
#pragma unroll
            for (int nt = 0; nt < 4; ++nt) {
                int row = nt * 16 + l15;
                int off = (row * 768 + kk * 64 + lq * 16) ^ ((row & 7) << 4);
                bf16x8 bf = *(const bf16x8*)(bb + off);
                // SWAPPED operands: D row (lq*4+r) = s-local, D col (l15) = t-local
                acc[nt] = __builtin_amdgcn_mfma_f32_16x16x32_bf16(bf, af[kk], acc[nt], 0, 0, 0);
            }
        }
        __syncthreads();

        {
            const int tl = w * 16 + l15;
            const float td = sqT_s[tl];
            const int t = t0 + tl;
#pragma unroll
            for (int nt = 0; nt < 4; ++nt) {
                const int sl = j * 64 + nt * 16 + lq * 4;
                ushort4_t h;
#pragma unroll
                for (int r = 0; r < 4; ++r) {
                    float d2 = td + sqS_s[sl + r] - 2.0f * acc[nt][r];
                    h[r] = f32_bf16(d2);
                }
                *(ushort4_t*)&d2w[((size_t)b << 20) + ((size_t)t << 10) + sbase + sl] = h;
            }
        }
    }
}

// ---------------- phase 2: persistent steady-state pipelined stream ----------------
// 512 blocks x 256 threads = 1<<17 threads; 64 elem/thread = 8 batches of 8.
// Ping-pong named register sets; LOAD(q+1) issued while batch q consumed ->
// >=1 batch (9.2 KB/wave) outstanding continuously; 8 iterations amortize the
// HBM-fill prologue. gt loads are NONTEMPORAL (streamed once; keep L2/L3 for
// z + d2w).
__launch_bounds__(256, 4)
__global__ void stream_loss(const float* __restrict__ gt,
                            const unsigned short* __restrict__ d2w,
                            const float* __restrict__ sigma,
                            float* __restrict__ partials) {
    __shared__ float red[4];
    const float LOG2E = 1.4426950408889634f;
    const float i0 = LOG2E * 0.5f / (sigma[0] * sigma[0]);
    const float i1 = LOG2E * 0.5f / (sigma[1] * sigma[1]);
    const float i2 = LOG2E * 0.5f / (sigma[2] * sigma[2]);
    const float i3 = LOG2E * 0.5f / (sigma[3] * sigma[3]);

    const int base = blockIdx.x * 256 + threadIdx.x;   // 1<<17 threads
    const f32x4* gt4 = (const f32x4*)gt;

    f32x4 gA[8], gB[8];
    unsigned int dA[8], dB[8];
    float acc = 0.f;

#define LOAD_BATCH(D, G, q)                                                       \
    _Pragma("unroll")                                                             \
    for (int i = 0; i < 8; ++i) D[i] = d2w[((size_t)((q) * 8 + i) << 17) + base]; \
    _Pragma("unroll")                                                             \
    for (int i = 0; i < 8; ++i)                                                   \
        G[i] = __builtin_nontemporal_load(gt4 + (((size_t)((q) * 8 + i) << 17) + base));

#define CONSUME_BATCH(D, G)                                                       \
    _Pragma("unroll")                                                             \
    for (int i = 0; i < 8; ++i) {                                                 \
        f32x4 gv = G[i];                                                          \
        float ddf = __uint_as_float(D[i] << 16);                                  \
        float kv = gv.x * gv.x * i0 + gv.y * gv.y * i1                            \
                 + gv.z * gv.z * i2 + gv.w * gv.w * i3;                           \
        acc += exp2f(-kv) * ddf;                                                  \
    }

    LOAD_BATCH(dA, gA, 0)
    LOAD_BATCH(dB, gB, 1)
    CONSUME_BATCH(dA, gA)  LOAD_BATCH(dA, gA, 2)
    CONSUME_BATCH(dB, gB)  LOAD_BATCH(dB, gB, 3)
    CONSUME_BATCH(dA, gA)  LOAD_BATCH(dA, gA, 4)
    CONSUME_BATCH(dB, gB)  LOAD_BATCH(dB, gB, 5)
    CONSUME_BATCH(dA, gA)  LOAD_BATCH(dA, gA, 6)
    CONSUME_BATCH(dB, gB)  LOAD_BATCH(dB, gB, 7)
    CONSUME_BATCH(dA, gA)
    CONSUME_BATCH(dB, gB)

#undef LOAD_BATCH
#undef CONSUME_BATCH

    int lane = threadIdx.x & 63, w = threadIdx.x >> 6;
#pragma unroll
    for (int off = 32; off; off >>= 1) acc += __shfl_down(acc, off);
    if (lane == 0) red[w] = acc;
    __syncthreads();
    if (threadIdx.x == 0) partials[blockIdx.x] = red[0] + red[1] + red[2] + red[3];
}

// ---------------- deterministic final reduction (512 partials) ----------------
__global__ void final_reduce(const float* __restrict__ partials, float* __restrict__ out) {
    __shared__ float red[4];
    int tid = threadIdx.x;  // 256
    float s = partials[tid] + partials[tid + 256];
#pragma unroll
    for (int off = 32; off; off >>= 1) s += __shfl_down(s, off);
    if ((tid & 63) == 0) red[tid >> 6] = s;
    __syncthreads();
    if (tid == 0) out[0] = (red[0] + red[1] + red[2] + red[3]) * (1.0f / 8388608.0f);
}

extern "C" void kernel_launch(void* const* d_in, const int* in_sizes, int n_in,
                              void* d_out, int out_size, void* d_ws, size_t ws_size,
                              hipStream_t stream) {
    const float* z     = (const float*)d_in[0];   // [8,1024,384]
    const float* gt    = (const float*)d_in[1];   // [8,1024,1024,4]
    const float* sigma = (const float*)d_in[2];   // [4]
    float* out = (float*)d_out;

    float* sq            = (float*)d_ws;                    // 8192 f32
    float* partials      = sq + 8192;                       // 512 f32
    unsigned short* d2w  = (unsigned short*)(sq + 10240);   // 8.4M bf16 = 16.8 MB

    prep_sq<<<8192, 64, 0, stream>>>(z, sq);
    gram_d2<<<512, 256, 0, stream>>>(z, sq, d2w);
    stream_loss<<<512, 256, 0, stream>>>(gt, d2w, sigma, partials);
    final_reduce<<<1, 256, 0, stream>>>(partials, out);
}

// Round 12
// 80.612 us; speedup vs baseline: 1.1029x; 1.0318x over previous
//
#include <hip/hip_runtime.h>
#include <hip/hip_bf16.h>

// B=8, T=1024, D=384, K=4
// loss = mean_{b,t,s} exp(-sum_k gt[b,t,s,k]^2/(2 sigma_k^2)) *
//        (||z[b,t]||^2 + ||z[b,s]||^2 - 2 z[b,t].z[b,s])
//
// Fused persistent kernel (r6 structure) with macro-unrolled ping-pong gt
// registers: no g=gn copy, no lambda/array-reference (rule #20), so gt(j+1)
// stays in flight for a full iteration.

typedef float  f32x4   __attribute__((ext_vector_type(4)));
typedef short  bf16x8  __attribute__((ext_vector_type(8)));
typedef unsigned short ushort4_t __attribute__((ext_vector_type(4)));

#define T_DIM 1024
#define D_DIM 384

__device__ __forceinline__ unsigned short f32_bf16(float f) {
    unsigned int u = __float_as_uint(f);
    u += 0x7FFFu + ((u >> 16) & 1u);      // RNE
    return (unsigned short)(u >> 16);
}

// ---------------- prep: sq[b*T+t] = sum_d z^2 (exact f32) ----------------
__global__ void prep_sq(const float* __restrict__ z, float* __restrict__ sq) {
    int row  = blockIdx.x;           // 0..8191
    int lane = threadIdx.x;          // 64
    const float* zr = z + (size_t)row * D_DIM;
    float s = 0.f;
#pragma unroll
    for (int q = 0; q < 6; ++q) {
        float x = zr[lane + 64 * q];
        s += x * x;
    }
#pragma unroll
    for (int off = 32; off; off >>= 1) s += __shfl_down(s, off);
    if (lane == 0) sq[row] = s;
}

// ---------------- fused persistent kernel ----------------
// grid 512 = 8 b * 16 t-tiles * 4 s-groups; block 256 (4 waves x 16 t-rows).
__launch_bounds__(256, 2)
__global__ void tile_loss(const float* __restrict__ z,
                          const float* __restrict__ gt,
                          const float* __restrict__ sigma,
                          const float* __restrict__ sq,
                          float* __restrict__ partials) {
    __shared__ unsigned short Blds[64 * D_DIM];   // 48 KiB, XOR-swizzled rows
    __shared__ float sq_s[T_DIM];                 // 4 KiB
    __shared__ float red[4];

    const int bid   = blockIdx.x;                 // 512
    const int b     = bid >> 6;
    const int tt    = (bid >> 2) & 15;
    const int sgrp  = bid & 3;
    const int t0    = tt * 64;
    const int sbase = sgrp * 256;

    const int tid  = threadIdx.x;
    const int lane = tid & 63, w = tid >> 6;
    const int l15  = lane & 15, lq = lane >> 4;

    const float* zb = z + (size_t)b * T_DIM * D_DIM;
    char* bb = (char*)Blds;

    const float LOG2E = 1.4426950408889634f;
    const float i0 = LOG2E * 0.5f / (sigma[0] * sigma[0]);
    const float i1 = LOG2E * 0.5f / (sigma[1] * sigma[1]);
    const float i2 = LOG2E * 0.5f / (sigma[2] * sigma[2]);
    const float i3 = LOG2E * 0.5f / (sigma[3] * sigma[3]);

    *(float4*)&sq_s[tid * 4] = *(const float4*)&sq[b * T_DIM + tid * 4];

    // A fragments once: row = t0 + w*16 + l15, cols kk*32 + lq*8 .. +8
    bf16x8 af[12];
    {
        const float* Ar = zb + (size_t)(t0 + w * 16 + l15) * D_DIM + lq * 8;
#pragma unroll
        for (int kk = 0; kk < 12; ++kk) {
            float4 lo = *(const float4*)(Ar + kk * 32);
            float4 hi = *(const float4*)(Ar + kk * 32 + 4);
            bf16x8 t;
            t[0] = (short)f32_bf16(lo.x); t[1] = (short)f32_bf16(lo.y);
            t[2] = (short)f32_bf16(lo.z); t[3] = (short)f32_bf16(lo.w);
            t[4] = (short)f32_bf16(hi.x); t[5] = (short)f32_bf16(hi.y);
            t[6] = (short)f32_bf16(hi.z); t[7] = (short)f32_bf16(hi.w);
            af[kk] = t;
        }
    }

    const float* gbase = gt + ((size_t)b << 22);  // b*1024*1024*4
    const int trow = t0 + w * 16 + lq * 4;        // this lane's 4 t-rows start

    float psum = 0.f;

// ---- macros: all indices compile-time; no references, no lambdas ----
#define STAGE(jn)                                                              \
    {                                                                          \
        const int s0_ = sbase + (jn) * 64;                                     \
        _Pragma("unroll")                                                      \
        for (int rp = 0; rp < 2; ++rp) {                                       \
            int row_ = rp * 32 + (tid >> 3);                                   \
            const float* src_ = zb + (size_t)(s0_ + row_) * D_DIM + (tid & 7) * 4; \
            int base_ = row_ * 768 + (tid & 7) * 8;                            \
            int sw_   = (row_ & 7) << 4;                                       \
            _Pragma("unroll")                                                  \
            for (int it = 0; it < 12; ++it) {                                  \
                float4 v_ = *(const float4*)(src_ + it * 32);                  \
                ushort4_t h_ = { f32_bf16(v_.x), f32_bf16(v_.y),               \
                                 f32_bf16(v_.z), f32_bf16(v_.w) };             \
                *(ushort4_t*)(bb + ((base_ + it * 64) ^ sw_)) = h_;            \
            }                                                                  \
        }                                                                      \
    }

#define LOADGT(G, jn)                                                          \
    _Pragma("unroll")                                                          \
    for (int nt = 0; nt < 4; ++nt) {                                           \
        _Pragma("unroll")                                                      \
        for (int r = 0; r < 4; ++r) {                                          \
            int s_ = sbase + (jn) * 64 + nt * 16 + l15;                        \
            G[nt][r] = __builtin_nontemporal_load(                             \
                (const f32x4*)(gbase + (((size_t)(trow + r) << 10) + s_) * 4));\
        }                                                                      \
    }

#define MFMA_STEP(ACC)                                                         \
    _Pragma("unroll")                                                          \
    for (int kk = 0; kk < 12; ++kk) {                                          \
        _Pragma("unroll")                                                      \
        for (int nt = 0; nt < 4; ++nt) {                                       \
            int row_ = nt * 16 + l15;                                          \
            int off_ = (row_ * 768 + kk * 64 + lq * 16) ^ ((row_ & 7) << 4);   \
            bf16x8 bf_ = *(const bf16x8*)(bb + off_);                          \
            ACC[nt] = __builtin_amdgcn_mfma_f32_16x16x32_bf16(af[kk], bf_, ACC[nt], 0, 0, 0); \
        }                                                                      \
    }

#define EPILOGUE(jc, ACC, G)                                                   \
    _Pragma("unroll")                                                          \
    for (int nt = 0; nt < 4; ++nt) {                                           \
        _Pragma("unroll")                                                      \
        for (int r = 0; r < 4; ++r) {                                          \
            int tg_ = trow + r;                                                \
            int sg_ = sbase + (jc) * 64 + nt * 16 + l15;                       \
            float d2_ = sq_s[tg_] + sq_s[sg_] - 2.0f * ACC[nt][r];             \
            f32x4 gv_ = G[nt][r];                                              \
            float kv_ = gv_.x * gv_.x * i0 + gv_.y * gv_.y * i1                \
                      + gv_.z * gv_.z * i2 + gv_.w * gv_.w * i3;               \
            psum += exp2f(-kv_) * d2_;                                         \
        }                                                                      \
    }

    f32x4 gA[4][4], gB[4][4];

    STAGE(0)
    __builtin_amdgcn_sched_barrier(0);
    LOADGT(gA, 0)
    __syncthreads();

    { // j = 0
        f32x4 acc[4] = {};
        MFMA_STEP(acc)
        __syncthreads();
        STAGE(1)
        __builtin_amdgcn_sched_barrier(0);
        LOADGT(gB, 1)
        __builtin_amdgcn_sched_barrier(0);
        EPILOGUE(0, acc, gA)
        __syncthreads();
    }
    { // j = 1
        f32x4 acc[4] = {};
        MFMA_STEP(acc)
        __syncthreads();
        STAGE(2)
        __builtin_amdgcn_sched_barrier(0);
        LOADGT(gA, 2)
        __builtin_amdgcn_sched_barrier(0);
        EPILOGUE(1, acc, gB)
        __syncthreads();
    }
    { // j = 2
        f32x4 acc[4] = {};
        MFMA_STEP(acc)
        __syncthreads();
        STAGE(3)
        __builtin_amdgcn_sched_barrier(0);
        LOADGT(gB, 3)
        __builtin_amdgcn_sched_barrier(0);
        EPILOGUE(2, acc, gA)
        __syncthreads();
    }
    { // j = 3
        f32x4 acc[4] = {};
        MFMA_STEP(acc)
        EPILOGUE(3, acc, gB)
    }

#undef STAGE
#undef LOADGT
#undef MFMA_STEP
#undef EPILOGUE

#pragma unroll
    for (int off = 32; off; off >>= 1) psum += __shfl_down(psum, off);
    if (lane == 0) red[w] = psum;
    __syncthreads();
    if (tid == 0) partials[bid] = red[0] + red[1] + red[2] + red[3];
}

// ---------------- deterministic final reduction (512 partials) ----------------
__global__ void final_reduce(const float* __restrict__ partials, float* __restrict__ out) {
    __shared__ float red[4];
    int tid = threadIdx.x;  // 256
    float s = partials[tid] + partials[tid + 256];
#pragma unroll
    for (int off = 32; off; off >>= 1) s += __shfl_down(s, off);
    if ((tid & 63) == 0) red[tid >> 6] = s;
    __syncthreads();
    if (tid == 0) out[0] = (red[0] + red[1] + red[2] + red[3]) * (1.0f / 8388608.0f);
}

extern "C" void kernel_launch(void* const* d_in, const int* in_sizes, int n_in,
                              void* d_out, int out_size, void* d_ws, size_t ws_size,
                              hipStream_t stream) {
    const float* z     = (const float*)d_in[0];   // [8,1024,384]
    const float* gt    = (const float*)d_in[1];   // [8,1024,1024,4]
    const float* sigma = (const float*)d_in[2];   // [4]
    float* out = (float*)d_out;

    float* sq       = (float*)d_ws;               // 8192 f32
    float* partials = sq + 8192;                  // 512 f32

    prep_sq<<<8192, 64, 0, stream>>>(z, sq);
    tile_loss<<<512, 256, 0, stream>>>(z, gt, sigma, sq, partials);
    final_reduce<<<1, 256, 0, stream>>>(partials, out);
}

// Round 13
// 77.395 us; speedup vs baseline: 1.1488x; 1.0416x over previous
//
#include <hip/hip_runtime.h>
#include <hip/hip_bf16.h>

// B=8, T=1024, D=384, K=4
// loss = mean_{b,t,s} exp(-sum_k gt[b,t,s,k]^2/(2 sigma_k^2)) *
//        (||z[b,t]||^2 + ||z[b,s]||^2 - 2 z[b,t].z[b,s])
//
// Barrier-free pure-TLP design: one wave = one 32x32 (t,s) tile, fully
// independent (no LDS, no __syncthreads in the hot kernel). z is
// pre-converted to bf16 in ws so MFMA fragments load directly.

typedef float  f32x4   __attribute__((ext_vector_type(4)));
typedef short  bf16x8  __attribute__((ext_vector_type(8)));

#define T_DIM 1024
#define D_DIM 384

__device__ __forceinline__ unsigned short f32_bf16(float f) {
    unsigned int u = __float_as_uint(f);
    u += 0x7FFFu + ((u >> 16) & 1u);      // RNE
    return (unsigned short)(u >> 16);
}

// ---------------- prep: sq[row] = ||z_row||^2 (f32) AND zbf = bf16(z) ----------------
__global__ void prep(const float* __restrict__ z, float* __restrict__ sq,
                     unsigned short* __restrict__ zbf) {
    int row  = blockIdx.x;           // 0..8191
    int lane = threadIdx.x;          // 64
    const float* zr = z + (size_t)row * D_DIM;
    unsigned short* zo = zbf + (size_t)row * D_DIM;
    float s = 0.f;
#pragma unroll
    for (int q = 0; q < 6; ++q) {
        float x = zr[lane + 64 * q];
        s += x * x;
        zo[lane + 64 * q] = f32_bf16(x);
    }
#pragma unroll
    for (int off = 32; off; off >>= 1) s += __shfl_down(s, off);
    if (lane == 0) sq[row] = s;
}

// ---------------- main: one wave per 32x32 tile, no barriers, no LDS ----------------
// 2048 blocks x 256 threads = 8192 waves = 8 b * 32 tt * 32 ss.
__launch_bounds__(256, 2)
__global__ void tile_loss(const unsigned short* __restrict__ zbf,
                          const float* __restrict__ gt,
                          const float* __restrict__ sigma,
                          const float* __restrict__ sq,
                          float* __restrict__ partials) {
    const int tid  = threadIdx.x;
    const int lane = tid & 63;
    const int wid  = blockIdx.x * 4 + (tid >> 6);   // 0..8191
    const int b    = wid >> 10;
    const int t0   = ((wid >> 5) & 31) * 32;
    const int s0   = (wid & 31) * 32;
    const int l15  = lane & 15, lq = lane >> 4;

    const float LOG2E = 1.4426950408889634f;
    const float i0 = LOG2E * 0.5f / (sigma[0] * sigma[0]);
    const float i1 = LOG2E * 0.5f / (sigma[1] * sigma[1]);
    const float i2 = LOG2E * 0.5f / (sigma[2] * sigma[2]);
    const float i3 = LOG2E * 0.5f / (sigma[3] * sigma[3]);

    // sq values (issued first; consumed last -> free under in-order vmcnt)
    const float* sqb = sq + b * T_DIM;
    float4 sqt0 = *(const float4*)&sqb[t0 + lq * 4];        // t rows, mt=0
    float4 sqt1 = *(const float4*)&sqb[t0 + 16 + lq * 4];   // mt=1
    float  sqs0 = sqb[s0 + l15];                            // s cols, nt=0
    float  sqs1 = sqb[s0 + 16 + l15];                       // nt=1

    // ---- MFMA: 12 k-steps, 2x2 16x16 subtiles; frags loaded per-kk (bf16 direct)
    const char* zB = (const char*)(zbf + (size_t)b * T_DIM * D_DIM);
    f32x4 acc00 = {}, acc01 = {}, acc10 = {}, acc11 = {};
#pragma unroll
    for (int kk = 0; kk < 12; ++kk) {
        const int co = kk * 64 + lq * 16;   // byte offset in 768B row
        bf16x8 a0 = *(const bf16x8*)(zB + (size_t)(t0 + l15)      * 768 + co);
        bf16x8 a1 = *(const bf16x8*)(zB + (size_t)(t0 + 16 + l15) * 768 + co);
        bf16x8 b0 = *(const bf16x8*)(zB + (size_t)(s0 + l15)      * 768 + co);
        bf16x8 b1 = *(const bf16x8*)(zB + (size_t)(s0 + 16 + l15) * 768 + co);
        acc00 = __builtin_amdgcn_mfma_f32_16x16x32_bf16(a0, b0, acc00, 0, 0, 0);
        acc01 = __builtin_amdgcn_mfma_f32_16x16x32_bf16(a0, b1, acc01, 0, 0, 0);
        acc10 = __builtin_amdgcn_mfma_f32_16x16x32_bf16(a1, b0, acc10, 0, 0, 0);
        acc11 = __builtin_amdgcn_mfma_f32_16x16x32_bf16(a1, b1, acc11, 0, 0, 0);
    }

    // ---- gt in 4 pipelined chunks of 4 f32x4 (16 VGPR each); consume in issue order
    const float* gbase = gt + ((size_t)b << 22);

#define LOADC(Q, mt, nt)                                                        \
    _Pragma("unroll")                                                           \
    for (int r = 0; r < 4; ++r)                                                 \
        Q[r] = __builtin_nontemporal_load((const f32x4*)(gbase +                \
            (((size_t)(t0 + (mt) * 16 + lq * 4 + r) << 10) + (s0 + (nt) * 16 + l15)) * 4));

#define CONSC(Q, ACC, SQT, SQS)                                                 \
    _Pragma("unroll")                                                           \
    for (int r = 0; r < 4; ++r) {                                               \
        float d2_ = SQT[r] + SQS - 2.0f * ACC[r];                               \
        f32x4 g_ = Q[r];                                                        \
        float kv_ = g_.x * g_.x * i0 + g_.y * g_.y * i1                         \
                  + g_.z * g_.z * i2 + g_.w * g_.w * i3;                        \
        psum += exp2f(-kv_) * d2_;                                              \
    }

    float psum = 0.f;
    f32x4 q0[4], q1[4];
    LOADC(q0, 0, 0)                      // chunk (mt0,nt0)
    LOADC(q1, 0, 1)                      // chunk (mt0,nt1)
    CONSC(q0, acc00, sqt0, sqs0)
    LOADC(q0, 1, 0)                      // chunk (mt1,nt0)
    CONSC(q1, acc01, sqt0, sqs1)
    LOADC(q1, 1, 1)                      // chunk (mt1,nt1)
    CONSC(q0, acc10, sqt1, sqs0)
    CONSC(q1, acc11, sqt1, sqs1)

#undef LOADC
#undef CONSC

    // per-wave reduction only (no LDS, no barrier)
#pragma unroll
    for (int off = 32; off; off >>= 1) psum += __shfl_down(psum, off);
    if (lane == 0) partials[wid] = psum;
}

// ---------------- deterministic final reduction (8192 partials) ----------------
__global__ void final_reduce(const float* __restrict__ partials, float* __restrict__ out) {
    __shared__ float red[4];
    int tid = threadIdx.x;  // 256
    float s = 0.f;
#pragma unroll
    for (int i = 0; i < 32; ++i) s += partials[tid + (i << 8)];
#pragma unroll
    for (int off = 32; off; off >>= 1) s += __shfl_down(s, off);
    if ((tid & 63) == 0) red[tid >> 6] = s;
    __syncthreads();
    if (tid == 0) out[0] = (red[0] + red[1] + red[2] + red[3]) * (1.0f / 8388608.0f);
}

extern "C" void kernel_launch(void* const* d_in, const int* in_sizes, int n_in,
                              void* d_out, int out_size, void* d_ws, size_t ws_size,
                              hipStream_t stream) {
    const float* z     = (const float*)d_in[0];   // [8,1024,384]
    const float* gt    = (const float*)d_in[1];   // [8,1024,1024,4]
    const float* sigma = (const float*)d_in[2];   // [4]
    float* out = (float*)d_out;

    float* sq            = (float*)d_ws;                       // 8192 f32
    float* partials      = sq + 8192;                          // 8192 f32
    unsigned short* zbf  = (unsigned short*)(sq + 16384);      // 8*1024*384 bf16 = 6 MB

    prep<<<8192, 64, 0, stream>>>(z, sq, zbf);
    tile_loss<<<2048, 256, 0, stream>>>(zbf, gt, sigma, sq, partials);
    final_reduce<<<1, 256, 0, stream>>>(partials, out);
}

// Round 14
// 75.122 us; speedup vs baseline: 1.1835x; 1.0303x over previous
//
#include <hip/hip_runtime.h>
#include <hip/hip_bf16.h>

// B=8, T=1024, D=384, K=4
// loss = mean_{b,t,s} exp(-sum_k gt[b,t,s,k]^2/(2 sigma_k^2)) *
//        (||z[b,t]||^2 + ||z[b,s]||^2 - 2 z[b,t].z[b,s])
//
// r6 structure + bf16 z (halves L3 z traffic) + chunked in-epilogue gt
// ping-pong (no cross-iteration gt registers -> no copy-drain, no spill).

typedef float  f32x4   __attribute__((ext_vector_type(4)));
typedef short  bf16x8  __attribute__((ext_vector_type(8)));

#define T_DIM 1024
#define D_DIM 384

__device__ __forceinline__ unsigned short f32_bf16(float f) {
    unsigned int u = __float_as_uint(f);
    u += 0x7FFFu + ((u >> 16) & 1u);      // RNE
    return (unsigned short)(u >> 16);
}

// ---------------- prep: sq[row] = ||z_row||^2 (f32) AND zbf = bf16(z) ----------------
__global__ void prep(const float* __restrict__ z, float* __restrict__ sq,
                     unsigned short* __restrict__ zbf) {
    int row  = blockIdx.x;           // 0..8191
    int lane = threadIdx.x;          // 64
    const float* zr = z + (size_t)row * D_DIM;
    unsigned short* zo = zbf + (size_t)row * D_DIM;
    float s = 0.f;
#pragma unroll
    for (int q = 0; q < 6; ++q) {
        float x = zr[lane + 64 * q];
        s += x * x;
        zo[lane + 64 * q] = f32_bf16(x);
    }
#pragma unroll
    for (int off = 32; off; off >>= 1) s += __shfl_down(s, off);
    if (lane == 0) sq[row] = s;
}

// ---------------- fused kernel: 64t x 256s per block ----------------
// grid 512 = 8 b * 16 tt * 4 sgrp; block 256 (4 waves x 16 t-rows).
// A-frags in regs (bf16 direct); B staged per-64-s-tile in swizzled LDS.
__launch_bounds__(256, 3)
__global__ void tile_loss(const unsigned short* __restrict__ zbf,
                          const float* __restrict__ gt,
                          const float* __restrict__ sigma,
                          const float* __restrict__ sq,
                          float* __restrict__ partials) {
    __shared__ unsigned short Blds[64 * D_DIM];   // 48 KiB, XOR-swizzled rows
    __shared__ float sqT_s[64];                   // block's 64 t-rows
    __shared__ float sqS_s[256];                  // block's 256 s-cols
    __shared__ float red[4];

    const int bid   = blockIdx.x;                 // 512
    const int b     = bid >> 6;
    const int tt    = (bid >> 2) & 15;
    const int sgrp  = bid & 3;
    const int t0    = tt * 64;
    const int sbase = sgrp * 256;

    const int tid  = threadIdx.x;
    const int lane = tid & 63, w = tid >> 6;
    const int l15  = lane & 15, lq = lane >> 4;

    const char* zB = (const char*)(zbf + (size_t)b * T_DIM * D_DIM);  // 768 B rows
    char* bb = (char*)Blds;

    const float LOG2E = 1.4426950408889634f;
    const float i0 = LOG2E * 0.5f / (sigma[0] * sigma[0]);
    const float i1 = LOG2E * 0.5f / (sigma[1] * sigma[1]);
    const float i2 = LOG2E * 0.5f / (sigma[2] * sigma[2]);
    const float i3 = LOG2E * 0.5f / (sigma[3] * sigma[3]);

    if (tid < 64) sqT_s[tid] = sq[b * T_DIM + t0 + tid];
    sqS_s[tid] = sq[b * T_DIM + sbase + tid];

    // ---- A fragments once (bf16 direct): row = t0 + w*16 + l15
    bf16x8 af[12];
    {
        const char* Ar = zB + (size_t)(t0 + w * 16 + l15) * 768 + lq * 16;
#pragma unroll
        for (int kk = 0; kk < 12; ++kk)
            af[kk] = *(const bf16x8*)(Ar + kk * 64);
    }

    const float* gbase = gt + ((size_t)b << 22);  // b*1024*1024*4
    const int trow = t0 + w * 16 + lq * 4;        // lane's 4 t-rows start
    const int srow = tid >> 2;                    // staging row 0..63
    const int scol = (tid & 3) * 16;              // staging byte col base

    float psum = 0.f;

// stage one 64-row B s-tile (bf16 copy, no conversion), XOR-swizzled
#define STAGE(jn)                                                              \
    {                                                                          \
        const char* src_ = zB + (size_t)(sbase + (jn) * 64 + srow) * 768 + scol; \
        const int lb_ = srow * 768 + scol;                                     \
        const int sw_ = (srow & 7) << 4;                                       \
        _Pragma("unroll")                                                      \
        for (int it = 0; it < 12; ++it) {                                      \
            bf16x8 v_ = *(const bf16x8*)(src_ + it * 64);                      \
            *(bf16x8*)(bb + ((lb_ + it * 64) ^ sw_)) = v_;                     \
        }                                                                      \
    }

#define LOADC(Q, jc, nt)                                                       \
    _Pragma("unroll")                                                          \
    for (int r = 0; r < 4; ++r)                                                \
        Q[r] = __builtin_nontemporal_load((const f32x4*)(gbase +               \
            (((size_t)(trow + r) << 10) + (sbase + (jc) * 64 + (nt) * 16 + l15)) * 4));

#define CONSC(Q, ACC, jc, nt)                                                  \
    _Pragma("unroll")                                                          \
    for (int r = 0; r < 4; ++r) {                                              \
        float d2_ = sqT_s[w * 16 + lq * 4 + r]                                 \
                  + sqS_s[(jc) * 64 + (nt) * 16 + l15] - 2.0f * ACC[r];        \
        f32x4 g_ = Q[r];                                                       \
        float kv_ = g_.x * g_.x * i0 + g_.y * g_.y * i1                        \
                  + g_.z * g_.z * i2 + g_.w * g_.w * i3;                       \
        psum += exp2f(-kv_) * d2_;                                             \
    }

    STAGE(0)
    __syncthreads();

#pragma unroll
    for (int j = 0; j < 4; ++j) {
        f32x4 acc0 = {}, acc1 = {}, acc2 = {}, acc3 = {};
#pragma unroll
        for (int kk = 0; kk < 12; ++kk) {
            const int co = kk * 64 + lq * 16;
            bf16x8 b0 = *(const bf16x8*)(bb + ((( 0 + l15) * 768 + co) ^ ((l15 & 7) << 4)));
            bf16x8 b1 = *(const bf16x8*)(bb + (((16 + l15) * 768 + co) ^ ((l15 & 7) << 4)));
            bf16x8 b2 = *(const bf16x8*)(bb + (((32 + l15) * 768 + co) ^ ((l15 & 7) << 4)));
            bf16x8 b3 = *(const bf16x8*)(bb + (((48 + l15) * 768 + co) ^ ((l15 & 7) << 4)));
            acc0 = __builtin_amdgcn_mfma_f32_16x16x32_bf16(af[kk], b0, acc0, 0, 0, 0);
            acc1 = __builtin_amdgcn_mfma_f32_16x16x32_bf16(af[kk], b1, acc1, 0, 0, 0);
            acc2 = __builtin_amdgcn_mfma_f32_16x16x32_bf16(af[kk], b2, acc2, 0, 0, 0);
            acc3 = __builtin_amdgcn_mfma_f32_16x16x32_bf16(af[kk], b3, acc3, 0, 0, 0);
        }
        __syncthreads();               // B reads done before restage
        if (j < 3) STAGE(j + 1)        // z loads drain fully before gt issues

        // chunked gt ping-pong: >=1 chunk (4KB/wave) in flight during consumes
        {
            f32x4 q0[4], q1[4];
            LOADC(q0, j, 0)
            LOADC(q1, j, 1)
            CONSC(q0, acc0, j, 0)
            LOADC(q0, j, 2)
            CONSC(q1, acc1, j, 1)
            LOADC(q1, j, 3)
            CONSC(q0, acc2, j, 2)
            CONSC(q1, acc3, j, 3)
        }
        if (j < 3) __syncthreads();    // stage(j+1) visible before next MFMA
    }

#undef STAGE
#undef LOADC
#undef CONSC

#pragma unroll
    for (int off = 32; off; off >>= 1) psum += __shfl_down(psum, off);
    if (lane == 0) red[w] = psum;
    __syncthreads();
    if (tid == 0) partials[bid] = red[0] + red[1] + red[2] + red[3];
}

// ---------------- deterministic final reduction (512 partials) ----------------
__global__ void final_reduce(const float* __restrict__ partials, float* __restrict__ out) {
    __shared__ float red[4];
    int tid = threadIdx.x;  // 256
    float s = partials[tid] + partials[tid + 256];
#pragma unroll
    for (int off = 32; off; off >>= 1) s += __shfl_down(s, off);
    if ((tid & 63) == 0) red[tid >> 6] = s;
    __syncthreads();
    if (tid == 0) out[0] = (red[0] + red[1] + red[2] + red[3]) * (1.0f / 8388608.0f);
}

extern "C" void kernel_launch(void* const* d_in, const int* in_sizes, int n_in,
                              void* d_out, int out_size, void* d_ws, size_t ws_size,
                              hipStream_t stream) {
    const float* z     = (const float*)d_in[0];   // [8,1024,384]
    const float* gt    = (const float*)d_in[1];   // [8,1024,1024,4]
    const float* sigma = (const float*)d_in[2];   // [4]
    float* out = (float*)d_out;

    float* sq            = (float*)d_ws;                   // 8192 f32
    float* partials      = sq + 8192;                      // 512 f32
    unsigned short* zbf  = (unsigned short*)(sq + 16384);  // 8*1024*384 bf16 = 6 MB

    prep<<<8192, 64, 0, stream>>>(z, sq, zbf);
    tile_loss<<<512, 256, 0, stream>>>(zbf, gt, sigma, sq, partials);
    final_reduce<<<1, 256, 0, stream>>>(partials, out);
}